// Round 9
// baseline (183.083 us; speedup 1.0000x reference)
//
#include <hip/hip_runtime.h>
#include <math.h>

// Problem constants
#define NB   4
#define CCH  256
#define HH   64
#define WW   64
#define GG   8
#define GCH  32
#define PP   9
#define HIN  66
#define WIN  66
#define HWSZ 4096            // H*W
#define NPIX 16384           // N*H*W

// Workspace element counts (ushort unless noted)
#define XP_ELEMS   (NB*HIN*WIN*CCH)     // 4460544
#define WINT_ELEMS (CCH*CCH)            // w_in^T  [n][k]
#define WOUTT_ELEMS (CCH*CCH)           // w_out^T [n][k]
#define WOMT_ELEMS (216*CCH)            // [w_off|w_mask]^T [col][k]
#define OFF_ELEMS  (NPIX*144)           // float
#define MSK_ELEMS  (NPIX*72)            // float

typedef __attribute__((ext_vector_type(8))) short bf16x8;
typedef __attribute__((ext_vector_type(4))) float f32x4;

__device__ __forceinline__ unsigned short f2bf(float f) {
    unsigned int u = __float_as_uint(f);
    unsigned int r = (u + 0x7FFFu + ((u >> 16) & 1u)) >> 16;
    return (unsigned short)r;
}
__device__ __forceinline__ float bf2f(unsigned short s) {
    return __uint_as_float(((unsigned int)s) << 16);
}

#define SDW_STRIDE 258

// ---------------------------------------------------------------------------
// Kernel 0: weight transposes (fp32 -> bf16, [n][k] layout) + xp ring zero.
// ---------------------------------------------------------------------------
__global__ __launch_bounds__(256) void k_prep(
    const float* __restrict__ w_in, const float* __restrict__ w_off,
    const float* __restrict__ w_mask, const float* __restrict__ w_out,
    unsigned short* __restrict__ win_t, unsigned short* __restrict__ womt,
    unsigned short* __restrict__ wout_t, unsigned short* __restrict__ xp)
{
    const int gtid = blockIdx.x * 256 + threadIdx.x;
    const int STRIDE = 128 * 256;         // 32768
    for (int i = gtid; i < 252928; i += STRIDE) {
        if (i < 65536) {
            int n = i & 255, k = i >> 8;
            win_t[n * 256 + k] = f2bf(w_in[i]);          // w_in[k][n]
        } else if (i < 131072) {
            int j = i - 65536;
            int n = j & 255, k = j >> 8;
            wout_t[n * 256 + k] = f2bf(w_out[j]);
        } else if (i < 186368) {
            int j = i - 131072;
            int k = j / 216, col = j - k * 216;
            float v = (col < 144) ? w_off[k * 144 + col]
                                  : w_mask[k * 72 + col - 144];
            womt[col * 256 + k] = f2bf(v);
        } else {
            int r = i - 186368;                 // [0, 66560)
            int seg = r >> 6, ln = r & 63;
            int n = seg / 260, rp = seg % 260;
            int h, w;
            if (rp < 66)       { h = 0;        w = rp; }
            else if (rp < 132) { h = 65;       w = rp - 66; }
            else if (rp < 196) { h = rp - 131; w = 0; }
            else               { h = rp - 195; w = 65; }
            uint2 z = make_uint2(0u, 0u);
            *(uint2*)&xp[(((size_t)n * HIN + h) * WIN + w) * CCH + ln * 4] = z;
        }
    }
}

// ---------------------------------------------------------------------------
// Kernel 1 (fused): depthwise 3x3 + LN + GELU + both projections (MFMA from
// LDS). R9: HALF-ROW blocks — 512 blocks x 512 threads, block = (n,h,half),
// 32 px x 256 ch, LDS ~47.6 KB -> 2 co-resident blocks/CU. Rationale: grid
// 256 = 1 block/CU meant every barrier idled the whole CU and conv (VMEM)
// could never overlap GEMM (MFMA); 2 independent blocks per CU overlap
// phases by construction (m114 mechanism). Phase-1 load structure is the
// proven R3 form (4 restructure attempts all failed to beat it).
// Horizontal halo at the half-row seam: predicated loads on lanes l==0/31.
// ---------------------------------------------------------------------------
__global__ __launch_bounds__(512) void k_dw_fused(
    const float* __restrict__ x, const float* __restrict__ w_dw,
    const float* __restrict__ b_dw, const float* __restrict__ ln_g,
    const float* __restrict__ ln_b, const float* __restrict__ b_in,
    const unsigned short* __restrict__ win_t, const unsigned short* __restrict__ womt,
    const float* __restrict__ b_off, const float* __restrict__ b_mask,
    unsigned short* __restrict__ xp, float* __restrict__ off,
    float* __restrict__ msk)
{
    __shared__ unsigned short sdw[32 * SDW_STRIDE];   // conv -> x1 (in-place)
    __shared__ unsigned short sxr[32 * SDW_STRIDE];   // raw x bf16 [px][c]
    __shared__ float r1s[16][32];
    __shared__ float r2s[16][32];
    __shared__ float mu_s[32];
    __shared__ float rs_s[32];
    __shared__ float swdw[2304];      // w_dw staged
    __shared__ float sbdw[256];       // b_dw staged

    const int b = blockIdx.x;
    const int tid = threadIdx.x;
    const int n    = b >> 7;
    const int h    = (b >> 1) & 63;
    const int w0   = (b & 1) * 32;
    const int wave = __builtin_amdgcn_readfirstlane(tid >> 6);   // 0..7, SGPR
    const int lane = tid & 63;
    const int l    = lane & 31;       // px within half-row
    const int cpar = lane >> 5;       // channel parity (0/1)

    // stage dw weights to LDS
    for (int i = tid; i < 2304; i += 512) swdw[i] = w_dw[i];
    if (tid < 256) sbdw[tid] = b_dw[tid];
    __syncthreads();

    const float* xn = x + (size_t)n * CCH * HWSZ;
    const bool h0ok = (h > 0);
    const bool h2ok = (h < HH - 1);

    float s1 = 0.f, s2 = 0.f;

    // ---- phase 1: depthwise 3x3, 2 channels per wave per iter ----
#pragma unroll 4
    for (int it = 0; it < 16; it++) {
        const int c = it * 16 + wave * 2 + cpar;
        const float* xc = xn + (size_t)c * HWSZ + h * WW + w0 + l;
        float v0 = h0ok ? xc[-WW] : 0.f;
        float v1 = xc[0];
        float v2 = h2ok ? xc[WW] : 0.f;

        const float* wk = &swdw[c * 9];
        float acc = sbdw[c];

        // seam halos (predicated: 2 lanes per wave issue these)
        float lh0 = 0.f, lh1 = 0.f, lh2 = 0.f;
        float rh0 = 0.f, rh1 = 0.f, rh2 = 0.f;
        if (l == 0 && w0 > 0) {
            lh1 = xc[-1];
            if (h0ok) lh0 = xc[-1 - WW];
            if (h2ok) lh2 = xc[-1 + WW];
        }
        if (l == 31 && w0 == 0) {
            rh1 = xc[1];
            if (h0ok) rh0 = xc[1 - WW];
            if (h2ok) rh2 = xc[1 + WW];
        }

        float t;
        t = __shfl_up(v0, 1);   float l0 = (l == 0)  ? lh0 : t;
        t = __shfl_down(v0, 1); float r0 = (l == 31) ? rh0 : t;
        acc += wk[0] * l0 + wk[1] * v0 + wk[2] * r0;

        t = __shfl_up(v1, 1);   float l1 = (l == 0)  ? lh1 : t;
        t = __shfl_down(v1, 1); float r1 = (l == 31) ? rh1 : t;
        acc += wk[3] * l1 + wk[4] * v1 + wk[5] * r1;

        t = __shfl_up(v2, 1);   float l2 = (l == 0)  ? lh2 : t;
        t = __shfl_down(v2, 1); float r2 = (l == 31) ? rh2 : t;
        acc += wk[6] * l2 + wk[7] * v2 + wk[8] * r2;

        s1 += acc;
        s2 += acc * acc;
        sdw[l * SDW_STRIDE + c] = f2bf(acc);
        sxr[l * SDW_STRIDE + c] = f2bf(v1);
    }

    r1s[wave * 2 + cpar][l] = s1;
    r2s[wave * 2 + cpar][l] = s2;
    __syncthreads();

    // ---- phase 2: LN stats per pixel ----
    if (tid < 32) {
        float a1 = 0.f, a2 = 0.f;
#pragma unroll
        for (int q = 0; q < 16; q++) { a1 += r1s[q][tid]; a2 += r2s[q][tid]; }
        float mu = a1 * (1.0f / 256.0f);
        float var = a2 * (1.0f / 256.0f) - mu * mu;
        mu_s[tid] = mu;
        rs_s[tid] = rsqrtf(var + 1e-5f);
    }
    __syncthreads();

    // ---- phase 3: LN + GELU, in-place into sdw ----
    {
        const int c0 = (tid & 63) * 4;
        float g4[4], b4[4];
#pragma unroll
        for (int i = 0; i < 4; i++) { g4[i] = ln_g[c0 + i]; b4[i] = ln_b[c0 + i]; }
#pragma unroll
        for (int pass = 0; pass < 4; pass++) {
            int w = wave + pass * 8;          // 0..31
            float mu = mu_s[w], rs = rs_s[w];
            unsigned short* row = &sdw[w * SDW_STRIDE + c0];
#pragma unroll
            for (int i = 0; i < 4; i++) {
                float v = (bf2f(row[i]) - mu) * rs * g4[i] + b4[i];
                row[i] = f2bf(0.5f * v * (1.0f + erff(v * 0.70710678118654752f)));
            }
        }
    }
    __syncthreads();

    // ---- phase 4: fused GEMMs from LDS (M = 32) ----
    const int r16  = lane & 15;
    const int quad = lane >> 4;
    const int wm   = wave >> 2;       // m-tile 0..1 (16 pixels each)
    const int wn   = wave & 3;        // n-quarter (4 x 16 cols each)

#define LOAD_A(frag, basep, koff)                                   \
    {                                                               \
        const unsigned short* ap_ = (basep) + (koff);               \
        ((unsigned int*)&(frag))[0] = *(const unsigned int*)&ap_[0];\
        ((unsigned int*)&(frag))[1] = *(const unsigned int*)&ap_[2];\
        ((unsigned int*)&(frag))[2] = *(const unsigned int*)&ap_[4];\
        ((unsigned int*)&(frag))[3] = *(const unsigned int*)&ap_[6];\
    }

    // gemm_in: bf16(x) @ win_t^T + b_in -> xp interior
    {
        f32x4 acc[4];
#pragma unroll
        for (int i = 0; i < 4; i++) acc[i] = (f32x4){0.f, 0.f, 0.f, 0.f};
        const unsigned short* arow = &sxr[(wm * 16 + r16) * SDW_STRIDE];

#pragma unroll
        for (int k0 = 0; k0 < CCH; k0 += 32) {
            bf16x8 a;
            LOAD_A(a, arow, k0 + quad * 8);
#pragma unroll
            for (int i = 0; i < 4; i++) {
                int co = (wn * 4 + i) * 16 + r16;
                bf16x8 bfr = *(const bf16x8*)&win_t[(size_t)co * CCH + k0 + quad * 8];
                acc[i] = __builtin_amdgcn_mfma_f32_16x16x32_bf16(a, bfr, acc[i], 0, 0, 0);
            }
        }

        unsigned short* xprow = xp + (((size_t)n * HIN + (h + 1)) * WIN + 1 + w0) * CCH;
#pragma unroll
        for (int i = 0; i < 4; i++) {
            int co = (wn * 4 + i) * 16 + r16;
            float bias = b_in[co];
#pragma unroll
            for (int r = 0; r < 4; r++) {
                int w = wm * 16 + quad * 4 + r;    // 0..31 local
                xprow[(size_t)w * CCH + co] = f2bf(acc[i][r] + bias);
            }
        }
    }

    // offmask: x1 @ womt^T + bias -> off (fp32), msk (fp32)
    {
        f32x4 acc[4];
#pragma unroll
        for (int i = 0; i < 4; i++) acc[i] = (f32x4){0.f, 0.f, 0.f, 0.f};
        const unsigned short* arow = &sdw[(wm * 16 + r16) * SDW_STRIDE];

#pragma unroll
        for (int k0 = 0; k0 < CCH; k0 += 32) {
            bf16x8 a;
            LOAD_A(a, arow, k0 + quad * 8);
#pragma unroll
            for (int i = 0; i < 4; i++) {
                int col = (wn * 4 + i) * 16 + r16;
                int colc = (col < 216) ? col : 215;   // clamp: safe addr
                bf16x8 bfr = *(const bf16x8*)&womt[(size_t)colc * CCH + k0 + quad * 8];
                acc[i] = __builtin_amdgcn_mfma_f32_16x16x32_bf16(a, bfr, acc[i], 0, 0, 0);
            }
        }

        const int sbase = n * HWSZ + h * WW + w0;
#pragma unroll
        for (int i = 0; i < 4; i++) {
            int col = (wn * 4 + i) * 16 + r16;
            if (col >= 216) continue;
            float bias = (col < 144) ? b_off[col] : b_mask[col - 144];
#pragma unroll
            for (int r = 0; r < 4; r++) {
                int w = wm * 16 + quad * 4 + r;
                int s = sbase + w;
                float v = acc[i][r] + bias;
                if (col < 144) off[(size_t)s * 144 + col] = v;
                else           msk[(size_t)s * 72 + col - 144] = v;
            }
        }
    }
#undef LOAD_A
}

// ---------------------------------------------------------------------------
// Kernel 2 (merged): deformable sampling -> agg in LDS -> output GEMM + BN
// + SiLU. 512 blocks x 512 threads, 32 px/block. (unchanged, passing)
// ---------------------------------------------------------------------------
__device__ __forceinline__ void acc8_tap(float* a, uint4 vv, float wgt) {
    a[0] += wgt * __uint_as_float(vv.x << 16);
    a[1] += wgt * __uint_as_float(vv.x & 0xffff0000u);
    a[2] += wgt * __uint_as_float(vv.y << 16);
    a[3] += wgt * __uint_as_float(vv.y & 0xffff0000u);
    a[4] += wgt * __uint_as_float(vv.z << 16);
    a[5] += wgt * __uint_as_float(vv.z & 0xffff0000u);
    a[6] += wgt * __uint_as_float(vv.w << 16);
    a[7] += wgt * __uint_as_float(vv.w & 0xffff0000u);
}

__global__ __launch_bounds__(512) void k_samp_out(
    const unsigned short* __restrict__ xp, const float* __restrict__ off,
    const float* __restrict__ msk, const unsigned short* __restrict__ wout_t,
    const float* __restrict__ b_out, const float* __restrict__ bn_g,
    const float* __restrict__ bn_b, const float* __restrict__ bn_mean,
    const float* __restrict__ bn_var, float* __restrict__ out)
{
    __shared__ int2   tco[2304];                 // 18432 B
    __shared__ float4 twt[2304];                 // 36864 B
    __shared__ unsigned short agg_l[32 * SDW_STRIDE];  // 16512 B

    const int tid = threadIdx.x;
    const int s0 = blockIdx.x * 32;
    const int n = s0 >> 12;
    const int hw0 = s0 & 4095;

    // ---- phase P: per-(pix,g) softmax + tap prep (threads 0..255) ----
    if (tid < 256) {
        const int pix = tid >> 3, g = tid & 7;
        const int s = s0 + pix;
        const int hw = s & 4095;
        const int h = hw >> 6, w = hw & 63;
        const float* mskp = msk + (size_t)s * 72 + g * 9;
        const float* offp = off + (size_t)s * 144 + g * 18;
        float e[9];
        float mx = -1e30f;
#pragma unroll
        for (int p = 0; p < PP; p++) { e[p] = mskp[p]; mx = fmaxf(mx, e[p]); }
        float sum = 0.f;
#pragma unroll
        for (int p = 0; p < PP; p++) { e[p] = __expf(e[p] - mx); sum += e[p]; }
        float rs = 1.0f / sum;
#pragma unroll
        for (int p = 0; p < PP; p++) {
            float m = e[p] * rs;
            float ox = offp[p * 2], oy = offp[p * 2 + 1];
            int i = p / 3, j = p - i * 3;
            float fx = (float)(w + i) + ox;
            float fy = (float)(h + j) + oy;
            float x0f = floorf(fx), y0f = floorf(fy);
            int x0 = (int)x0f, y0 = (int)y0f;
            float wx = fx - x0f, wy = fy - y0f;
            float w00 = (1.f - wx) * (1.f - wy) * m;
            float w10 = wx * (1.f - wy) * m;
            float w01 = (1.f - wx) * wy * m;
            float w11 = wx * wy * m;
            int x1c = x0 + 1, y1c = y0 + 1;
            if (!((x0  >= 0) && (x0  < WIN))) { w00 = 0.f; w01 = 0.f; }
            if (!((x1c >= 0) && (x1c < WIN))) { w10 = 0.f; w11 = 0.f; }
            if (!((y0  >= 0) && (y0  < HIN))) { w00 = 0.f; w10 = 0.f; }
            if (!((y1c >= 0) && (y1c < HIN))) { w01 = 0.f; w11 = 0.f; }
            int cx0 = min(max(x0, 0), WIN - 1), cx1 = min(max(x1c, 0), WIN - 1);
            int cy0 = min(max(y0, 0), HIN - 1), cy1 = min(max(y1c, 0), HIN - 1);
            tco[tid * 9 + p] = make_int2(cx0 | (cx1 << 16), cy0 | (cy1 << 16));
            twt[tid * 9 + p] = make_float4(w00, w10, w01, w11);
        }
    }
    __syncthreads();

    // ---- phase T: taps, 2 passes of 16 px ----
    const int l5 = tid & 31;
    const int g = l5 >> 2, c8 = l5 & 3;
    const unsigned short* base = xp + (size_t)n * HIN * WIN * CCH + g * GCH + c8 * 8;

#pragma unroll
    for (int pp = 0; pp < 2; pp++) {
        const int pix = pp * 16 + (tid >> 5);
        const int tbase = pix * 72 + g * 9;

        float a[8];
#pragma unroll
        for (int i = 0; i < 8; i++) a[i] = 0.f;

#pragma unroll
        for (int p = 0; p < PP; p++) {
            int2 cc = tco[tbase + p];
            float4 wt = twt[tbase + p];
            int cx0 = cc.x & 0xFFFF, cx1 = cc.x >> 16;
            int cy0 = cc.y & 0xFFFF, cy1 = cc.y >> 16;
            const unsigned short* r0 = base + (size_t)(cy0 * WIN) * CCH;
            const unsigned short* r1 = base + (size_t)(cy1 * WIN) * CCH;
            uint4 v00 = *(const uint4*)&r0[(size_t)cx0 * CCH];
            uint4 v10 = *(const uint4*)&r0[(size_t)cx1 * CCH];
            uint4 v01 = *(const uint4*)&r1[(size_t)cx0 * CCH];
            uint4 v11 = *(const uint4*)&r1[(size_t)cx1 * CCH];
            acc8_tap(a, v00, wt.x);
            acc8_tap(a, v10, wt.y);
            acc8_tap(a, v01, wt.z);
            acc8_tap(a, v11, wt.w);
        }

        unsigned int* dst = (unsigned int*)&agg_l[pix * SDW_STRIDE + g * GCH + c8 * 8];
        dst[0] = (unsigned int)f2bf(a[0]) | ((unsigned int)f2bf(a[1]) << 16);
        dst[1] = (unsigned int)f2bf(a[2]) | ((unsigned int)f2bf(a[3]) << 16);
        dst[2] = (unsigned int)f2bf(a[4]) | ((unsigned int)f2bf(a[5]) << 16);
        dst[3] = (unsigned int)f2bf(a[6]) | ((unsigned int)f2bf(a[7]) << 16);
    }
    __syncthreads();

    // ---- phase G: 32x256 GEMM from LDS-agg + BN + SiLU -> out ----
    {
        const int wave = tid >> 6;        // 0..7
        const int lane = tid & 63;
        const int r16  = lane & 15;
        const int quad = lane >> 4;
        const int wm   = wave >> 2;       // m-tile 0..1 (16 px each)
        const int wn   = wave & 3;        // 64-col group

        f32x4 acc[4];
#pragma unroll
        for (int i = 0; i < 4; i++) acc[i] = (f32x4){0.f, 0.f, 0.f, 0.f};

        const unsigned short* arow = &agg_l[(wm * 16 + r16) * SDW_STRIDE];

#pragma unroll
        for (int k0 = 0; k0 < CCH; k0 += 32) {
            bf16x8 a;
            {
                const unsigned short* ap_ = arow + k0 + quad * 8;
                ((unsigned int*)&a)[0] = *(const unsigned int*)&ap_[0];
                ((unsigned int*)&a)[1] = *(const unsigned int*)&ap_[2];
                ((unsigned int*)&a)[2] = *(const unsigned int*)&ap_[4];
                ((unsigned int*)&a)[3] = *(const unsigned int*)&ap_[6];
            }
#pragma unroll
            for (int nt = 0; nt < 4; nt++) {
                int co = wn * 64 + nt * 16 + r16;
                bf16x8 bfr = *(const bf16x8*)&wout_t[(size_t)co * CCH + k0 + quad * 8];
                acc[nt] = __builtin_amdgcn_mfma_f32_16x16x32_bf16(a, bfr, acc[nt], 0, 0, 0);
            }
        }

#pragma unroll
        for (int nt = 0; nt < 4; nt++) {
            int co = wn * 64 + nt * 16 + r16;
            float mean = bn_mean[co];
            float rstd = rsqrtf(bn_var[co] + 1e-5f);
            float gg = bn_g[co], bb = bn_b[co], bo = b_out[co];
            int hwb = hw0 + wm * 16 + quad * 4;
            float tmp[4];
#pragma unroll
            for (int r = 0; r < 4; r++) {
                float y = acc[nt][r] + bo;
                float yh = (y - mean) * rstd * gg + bb;
                tmp[r] = yh / (1.0f + __expf(-yh));
            }
            float4 v = make_float4(tmp[0], tmp[1], tmp[2], tmp[3]);
            *(float4*)&out[((size_t)n * CCH + co) * HWSZ + hwb] = v;
        }
    }
}

// ---------------------------------------------------------------------------
extern "C" void kernel_launch(void* const* d_in, const int* in_sizes, int n_in,
                              void* d_out, int out_size, void* d_ws, size_t ws_size,
                              hipStream_t stream)
{
    const float* x       = (const float*)d_in[0];
    const float* w_in    = (const float*)d_in[1];
    const float* b_in    = (const float*)d_in[2];
    const float* w_dw    = (const float*)d_in[3];
    const float* b_dw    = (const float*)d_in[4];
    const float* ln_g    = (const float*)d_in[5];
    const float* ln_b    = (const float*)d_in[6];
    const float* w_off   = (const float*)d_in[7];
    const float* b_off   = (const float*)d_in[8];
    const float* w_mask  = (const float*)d_in[9];
    const float* b_mask  = (const float*)d_in[10];
    const float* w_out   = (const float*)d_in[11];
    const float* b_out   = (const float*)d_in[12];
    const float* bn_g    = (const float*)d_in[13];
    const float* bn_b    = (const float*)d_in[14];
    const float* bn_mean = (const float*)d_in[15];
    const float* bn_var  = (const float*)d_in[16];
    float* out = (float*)d_out;

    unsigned short* xp     = (unsigned short*)d_ws;
    unsigned short* win_t  = xp + XP_ELEMS;
    unsigned short* wout_t = win_t + WINT_ELEMS;
    unsigned short* womt   = wout_t + WOUTT_ELEMS;
    float* off = (float*)(womt + WOMT_ELEMS);
    float* msk = off + OFF_ELEMS;
    // total ~24 MB

    k_prep<<<dim3(128), 256, 0, stream>>>(w_in, w_off, w_mask, w_out,
                                          win_t, womt, wout_t, xp);
    k_dw_fused<<<dim3(512), 512, 0, stream>>>(x, w_dw, b_dw, ln_g, ln_b, b_in,
                                              win_t, womt, b_off, b_mask,
                                              xp, off, msk);
    k_samp_out<<<dim3(512), 512, 0, stream>>>(xp, off, msk, wout_t, b_out,
                                              bn_g, bn_b, bn_mean, bn_var, out);
}